// Round 2
// baseline (233.609 us; speedup 1.0000x reference)
//
#include <hip/hip_runtime.h>
#include <math.h>

#define NSITES 65536
#define WIN 4096
#define NW 16          // windows per sweep
#define RMAX 64        // tracked rounds per window (observed depth ~7)

// ws layout:
//   recpk  uint2[2*NSITES]   1048576 B  ({site, uniform-bits} per sorted slot, per sweep)
//   ends   int  [NW*RMAX]       4096 B  (cumulative round boundaries, per window)

// wave-aggregated atomic rank: position for value v in counter array c
// (1-based values, v <= vmax; vmax wave-uniform).
__device__ __forceinline__ int agg_pos(int v, int* c, int vmax) {
  int pos = 0;
  const int lane = threadIdx.x & 63;
  for (int vv = 1; vv <= vmax; ++vv) {
    unsigned long long m = __ballot(v == vv);
    if (m) {
      int leader = __ffsll((long long)m) - 1;
      int base = 0;
      if (lane == leader) base = atomicAdd(&c[vv], (int)__popcll(m));
      base = __shfl(base, leader);
      if (v == vv) pos = base + (int)__popcll(m & ((1ull << lane) - 1ull));
    }
  }
  return pos;
}

// ---------------------------------------------------------------------------
// Kernel A: per-window DAG leveling + counting sort + packed record gather.
// One 1024-thread block per window; window-local position grid in LDS.
// (UNCHANGED — next round attacks A with its own counters once it surfaces.)
// ---------------------------------------------------------------------------
__global__ __launch_bounds__(1024) void GibbsSched_kernel(
    const int* __restrict__ perm, const float* __restrict__ uni,
    uint2* __restrict__ recpk, int* __restrict__ ends) {
  __shared__ unsigned short posg[NSITES];  // 128 KiB: local pos+1, 0 = absent
  __shared__ unsigned short lvl[WIN];      // 8 KiB
  __shared__ int cnt[RMAX + 1], coff[RMAX + 1];
  __shared__ int chg, bmax;
  const int tid = threadIdx.x;
  const int w = blockIdx.x;
  const int wbase = w * WIN;

  for (int g = tid; g < NSITES / 8; g += 1024)  // 8 ushorts per uint4
    ((uint4*)posg)[g] = make_uint4(0u, 0u, 0u, 0u);
  for (int i = tid; i <= RMAX; i += 1024) { cnt[i] = 0; coff[i] = 0; }
  if (tid == 0) bmax = 0;
  __syncthreads();

  int uvk[4];
#pragma unroll
  for (int k = 0; k < 4; ++k) {
    const int lt = tid + k * 1024;
    uvk[k] = perm[wbase + lt];
    posg[uvk[k]] = (unsigned short)(lt + 1);  // sites unique within a sweep
  }
  __syncthreads();

  unsigned short pred[4][8];
  int myl[4];
#pragma unroll
  for (int k = 0; k < 4; ++k) {
    const int lt = tid + k * 1024;
    const int uv = uvk[k], u = uv >> 8, v = uv & 255;
    const int um = u ? u - 1 : 0, up = u < 255 ? u + 1 : 255;
    const int vm = v ? v - 1 : 0, vp = v < 255 ? v + 1 : 255;
    const int nb8[8] = {(um << 8) | vm, (um << 8) | v, (um << 8) | vp,
                        (u << 8) | vm,                 (u << 8) | vp,
                        (up << 8) | vm, (up << 8) | v, (up << 8) | vp};
#pragma unroll
    for (int j = 0; j < 8; ++j) {
      const int p = posg[nb8[j]];  // clipped dup == self -> p-1==lt, excluded
      pred[k][j] = (p && p - 1 < lt) ? (unsigned short)(p - 1)
                                     : (unsigned short)0xFFFF;
    }
    lvl[lt] = 1;
    myl[k] = 1;
  }
  __syncthreads();

  // monotone Jacobi relaxation to the unique longest-path fixpoint
  for (int pass = 0; pass < 128; ++pass) {
    if (tid == 0) chg = 0;
    __syncthreads();
    bool ch = false;
#pragma unroll
    for (int k = 0; k < 4; ++k) {
      int m = 0;
#pragma unroll
      for (int j = 0; j < 8; ++j) {
        const unsigned short p = pred[k][j];
        if (p != 0xFFFF) m = max(m, (int)lvl[p]);
      }
      const int nl = m + 1;  // levels only grow
      if (nl != myl[k]) {
        myl[k] = nl;
        lvl[tid + k * 1024] = (unsigned short)nl;
        ch = true;
      }
    }
    if (ch) chg = 1;
    __syncthreads();
    if (chg == 0) break;  // full no-change pass == converged
  }

#pragma unroll
  for (int k = 0; k < 4; ++k) atomicMax(&bmax, myl[k]);
  __syncthreads();
  const int vmax = bmax;

#pragma unroll
  for (int k = 0; k < 4; ++k) (void)agg_pos(myl[k], cnt, vmax);  // histogram
  __syncthreads();
  if (tid == 0) {
    int e = 0;
    for (int r = 0; r < RMAX; ++r) {  // cnt[0]==0
      coff[r] = e;
      e += cnt[r];
      ends[w * RMAX + r] = e;  // cumulative end through round r
    }
  }
  __syncthreads();

#pragma unroll
  for (int k = 0; k < 4; ++k) {
    const int pos = agg_pos(myl[k], coff, vmax);
    const int lt = tid + k * 1024;
    const int gp = wbase + pos;
    recpk[gp] = make_uint2((unsigned)uvk[k],
                           __float_as_uint(uni[wbase + lt]));          // sweep 0
    recpk[NSITES + gp] = make_uint2((unsigned)uvk[k],
                                    __float_as_uint(uni[NSITES + wbase + lt]));
  }
}

// ---------------------------------------------------------------------------
// Kernel B: executor — 1 block x 1024 threads.
// Records register-resident (4 x uint2/thread, double-buffered across windows).
// NEW this round: rounds are phase-split into read-all -> compute-all ->
// write-all. Legal because same-level sites are never neighbors (a,b neighbors
// with pos(a)<pos(b) forces level(b)>level(a)), so within a round no record's
// write aliases another's read set. All 24 row dwords issue before one
// lgkmcnt wait; all ctab reads overlap; then the byte writes; one barrier.
// ---------------------------------------------------------------------------
__device__ __forceinline__ void run_rounds(unsigned char* cell,
                                           const unsigned int* cellw,
                                           const float4* ctab, const int* le,
                                           const uint2 (&R)[4], int tid) {
  int b = 0, e = le[1];
  for (int rd = 1; rd < RMAX; ++rd) {
    if (b >= WIN) break;  // uniform: window complete
    // pipeline: fetch next round's bounds before the barrier
    const int nb = e;
    const int ne = (rd + 1 < RMAX) ? le[rd + 1] : e;

    bool act[4];
    unsigned rT0[4], rT1[4], rM0[4], rM1[4], rB0[4], rB1[4];
    int sh0[4], shv[4], shp[4];
    // phase 1: issue ALL row reads (no LDS writes in between -> overlap)
#pragma unroll
    for (int k = 0; k < 4; ++k) {
      const int s = tid + (k << 10);
      act[k] = (s >= b && s < e);
      if (act[k]) {
        const unsigned uvv = R[k].x;
        const int u = (int)(uvv >> 8), v = (int)(uvv & 255u);
        const int um = u ? u - 1 : 0, up = u < 255 ? u + 1 : 255;
        const int vm = v ? v - 1 : 0, vp = v < 255 ? v + 1 : 255;
        const int cb = vm >> 2;            // dword col of 8-byte window start
        sh0[k] = (vm & 3) << 3;
        shv[k] = (v - vm) << 3;            // 0 or 8
        shp[k] = (vp - vm) << 3;           // 8 or 16 (or 8 at right border)
        const unsigned int* rwT = cellw + (um << 6) + cb;
        const unsigned int* rwM = cellw + (u << 6) + cb;
        const unsigned int* rwB = cellw + (up << 6) + cb;
        rT0[k] = rwT[0]; rT1[k] = rwT[1];
        rM0[k] = rwM[0]; rM1[k] = rwM[1];
        rB0[k] = rwB[0]; rB1[k] = rwB[1];
      }
    }
    // phase 2: histograms + ctab lookups (reads only -> ctab reads overlap)
    float4 cv[4];
#pragma unroll
    for (int k = 0; k < 4; ++k) {
      if (act[k]) {
        int acc = 0;  // per-class counts in nibbles
        {  // top row: cols vm, v, vp (clipped dups included, as reference)
          const unsigned long long wd =
              ((unsigned long long)rT1[k] << 32) | (unsigned long long)rT0[k];
          const unsigned wl = (unsigned)(wd >> sh0[k]);
          acc += 1 << ((wl & 255u) << 2);
          acc += 1 << (((wl >> shv[k]) & 255u) << 2);
          acc += 1 << (((wl >> shp[k]) & 255u) << 2);
        }
        {  // middle row: cols vm, vp only (true center excluded exactly once)
          const unsigned long long wd =
              ((unsigned long long)rM1[k] << 32) | (unsigned long long)rM0[k];
          const unsigned wl = (unsigned)(wd >> sh0[k]);
          acc += 1 << ((wl & 255u) << 2);
          acc += 1 << (((wl >> shp[k]) & 255u) << 2);
        }
        {  // bottom row: cols vm, v, vp
          const unsigned long long wd =
              ((unsigned long long)rB1[k] << 32) | (unsigned long long)rB0[k];
          const unsigned wl = (unsigned)(wd >> sh0[k]);
          acc += 1 << ((wl & 255u) << 2);
          acc += 1 << (((wl >> shv[k]) & 255u) << 2);
          acc += 1 << (((wl >> shp[k]) & 255u) << 2);
        }
        const int n0 = acc & 15, n1 = (acc >> 4) & 15, n2 = (acc >> 8) & 15;
        cv[k] = ctab[n0 + 9 * n1 + 81 * n2];
      }
    }
    // phase 3: categorical sample + byte writes
#pragma unroll
    for (int k = 0; k < 4; ++k) {
      if (act[k]) {
        const float r = __uint_as_float(R[k].y);
        const float4 c = cv[k];
        int cnt = (c.x < r) ? 1 : 0;
        cnt += (c.y < r) ? 1 : 0;
        cnt += (c.z < r) ? 1 : 0;
        cnt += (c.w < r) ? 1 : 0;
        cell[R[k].x] = (unsigned char)cnt;  // 0..4
      }
    }
    __syncthreads();  // round rd writes before round rd+1 reads
    b = nb;
    e = ne;
  }
}

__global__ __launch_bounds__(1024) void GibbsSampler_90443421319469_kernel(
    const int* __restrict__ Xi, const uint2* __restrict__ recpk,
    const float* __restrict__ betap, const int* __restrict__ ends,
    int* __restrict__ out) {
#pragma clang fp contract(off)
  __shared__ __align__(16) unsigned int cellw[NSITES / 4];  // 64 KiB lattice
  __shared__ float4 ctab[732];                              // 11.7 KiB
  __shared__ int lend[NW * RMAX];                           // 4 KiB
  unsigned char* cell = (unsigned char*)cellw;
  const int tid = threadIdx.x;
  const float beta = betap[0];

  // issue window-0 record loads first so HBM latency hides under LDS init
  uint2 ra[4], rb[4];
#pragma unroll
  for (int k = 0; k < 4; ++k) ra[k] = recpk[tid + (k << 10)];

  for (int g = tid; g < NSITES / 4; g += 1024) {
    int4 x = ((const int4*)Xi)[g];
    // pack 4 int32 cells into one dword (byte lanes)
    cellw[g] = (unsigned)(x.x & 255) | ((unsigned)(x.y & 255) << 8) |
               ((unsigned)(x.z & 255) << 16) | ((unsigned)(x.w & 255) << 24);
  }
  lend[tid] = ends[tid];  // NW*RMAX == 1024
  // cumulative softmax table: bit-identical to per-update reference math
  for (int t = tid; t < 729; t += 1024) {
    const int n0 = t % 9, n1 = (t / 9) % 9, n2 = t / 81;
    const int n3 = 8 - n0 - n1 - n2;
    float4 val = make_float4(2.f, 2.f, 2.f, 2.f);  // unreachable combos
    if (n3 >= 0) {
      const int mx = max(max(n0, n1), max(n2, n3));
      const float xm = beta * (float)mx;   // fl(beta*mx), no FMA (contract off)
      const float x0 = beta * (float)n0;
      const float x1 = beta * (float)n1;
      const float x2 = beta * (float)n2;
      const float x3 = beta * (float)n3;
      const float e0 = (float)exp((double)(x0 - xm));
      const float e1 = (float)exp((double)(x1 - xm));
      const float e2 = (float)exp((double)(x2 - xm));
      const float e3 = (float)exp((double)(x3 - xm));
      const float s = ((e0 + e1) + e2) + e3;  // sequential sum, like np/XLA
      const float c0 = e0 / s;                // IEEE f32 divides, like ref
      const float c1 = c0 + e1 / s;
      const float c2 = c1 + e2 / s;
      const float c3 = c2 + e3 / s;
      val = make_float4(c0, c1, c2, c3);
    }
    ctab[t] = val;
  }
  __syncthreads();

  for (int w = 0; w < 2 * NW; ++w) {
    const int ww = w & (NW - 1);
    const int* le = &lend[ww * RMAX];
    const int wn = w + 1;  // prefetch target (guarded; pointer calc only)
    const uint2* rpn = recpk + (wn >> 4) * NSITES + (wn & (NW - 1)) * WIN;
    if ((w & 1) == 0) {
      if (wn < 2 * NW) {
#pragma unroll
        for (int k = 0; k < 4; ++k) rb[k] = rpn[tid + (k << 10)];
      }
      run_rounds(cell, cellw, ctab, le, ra, tid);
    } else {
      if (wn < 2 * NW) {
#pragma unroll
        for (int k = 0; k < 4; ++k) ra[k] = rpn[tid + (k << 10)];
      }
      run_rounds(cell, cellw, ctab, le, rb, tid);
    }
  }

  for (int g = tid; g < NSITES / 4; g += 1024) {
    const unsigned p = cellw[g];
    int4 o;
    o.x = (int)(p & 255u);
    o.y = (int)((p >> 8) & 255u);
    o.z = (int)((p >> 16) & 255u);
    o.w = (int)((p >> 24) & 255u);
    ((int4*)out)[g] = o;
  }
}

extern "C" void kernel_launch(void* const* d_in, const int* in_sizes, int n_in,
                              void* d_out, int out_size, void* d_ws,
                              size_t ws_size, hipStream_t stream) {
  const int* Xi = (const int*)d_in[0];
  const int* perm = (const int*)d_in[1];
  const float* uni = (const float*)d_in[2];
  const float* beta = (const float*)d_in[3];
  int* out = (int*)d_out;

  char* ws = (char*)d_ws;
  uint2* recpk = (uint2*)ws;                 // 1 MiB
  int* ends = (int*)(ws + 2 * NSITES * 8);   // 4 KiB

  GibbsSched_kernel<<<dim3(NW), dim3(1024), 0, stream>>>(perm, uni, recpk,
                                                         ends);
  GibbsSampler_90443421319469_kernel<<<dim3(1), dim3(1024), 0, stream>>>(
      Xi, recpk, beta, ends, out);
}

// Round 3
// 230.205 us; speedup vs baseline: 1.0148x; 1.0148x over previous
//
#include <hip/hip_runtime.h>
#include <math.h>

#define NSITES 65536
#define WIN 4096
#define NW 16          // windows per sweep
#define RMAX 64        // tracked rounds per window (observed depth ~7)

// ws layout:
//   recpk  uint2[2*NSITES]   1048576 B  ({site, uniform-bits} per sorted slot, per sweep)
//   ends   int  [NW*RMAX]       4096 B  (cumulative round boundaries, per window)

// wave-aggregated atomic rank: position for value v in counter array c
// (1-based values, v <= vmax; vmax wave-uniform).
__device__ __forceinline__ int agg_pos(int v, int* c, int vmax) {
  int pos = 0;
  const int lane = threadIdx.x & 63;
  for (int vv = 1; vv <= vmax; ++vv) {
    unsigned long long m = __ballot(v == vv);
    if (m) {
      int leader = __ffsll((long long)m) - 1;
      int base = 0;
      if (lane == leader) base = atomicAdd(&c[vv], (int)__popcll(m));
      base = __shfl(base, leader);
      if (v == vv) pos = base + (int)__popcll(m & ((1ull << lane) - 1ull));
    }
  }
  return pos;
}

// ---------------------------------------------------------------------------
// Kernel A: per-window DAG leveling + counting sort + packed record gather.
// One 1024-thread block per window; window-local position grid in LDS.
// (UNCHANGED — single-variable discipline; attacked once its counters surface.)
// ---------------------------------------------------------------------------
__global__ __launch_bounds__(1024) void GibbsSched_kernel(
    const int* __restrict__ perm, const float* __restrict__ uni,
    uint2* __restrict__ recpk, int* __restrict__ ends) {
  __shared__ unsigned short posg[NSITES];  // 128 KiB: local pos+1, 0 = absent
  __shared__ unsigned short lvl[WIN];      // 8 KiB
  __shared__ int cnt[RMAX + 1], coff[RMAX + 1];
  __shared__ int chg, bmax;
  const int tid = threadIdx.x;
  const int w = blockIdx.x;
  const int wbase = w * WIN;

  for (int g = tid; g < NSITES / 8; g += 1024)  // 8 ushorts per uint4
    ((uint4*)posg)[g] = make_uint4(0u, 0u, 0u, 0u);
  for (int i = tid; i <= RMAX; i += 1024) { cnt[i] = 0; coff[i] = 0; }
  if (tid == 0) bmax = 0;
  __syncthreads();

  int uvk[4];
#pragma unroll
  for (int k = 0; k < 4; ++k) {
    const int lt = tid + k * 1024;
    uvk[k] = perm[wbase + lt];
    posg[uvk[k]] = (unsigned short)(lt + 1);  // sites unique within a sweep
  }
  __syncthreads();

  unsigned short pred[4][8];
  int myl[4];
#pragma unroll
  for (int k = 0; k < 4; ++k) {
    const int lt = tid + k * 1024;
    const int uv = uvk[k], u = uv >> 8, v = uv & 255;
    const int um = u ? u - 1 : 0, up = u < 255 ? u + 1 : 255;
    const int vm = v ? v - 1 : 0, vp = v < 255 ? v + 1 : 255;
    const int nb8[8] = {(um << 8) | vm, (um << 8) | v, (um << 8) | vp,
                        (u << 8) | vm,                 (u << 8) | vp,
                        (up << 8) | vm, (up << 8) | v, (up << 8) | vp};
#pragma unroll
    for (int j = 0; j < 8; ++j) {
      const int p = posg[nb8[j]];  // clipped dup == self -> p-1==lt, excluded
      pred[k][j] = (p && p - 1 < lt) ? (unsigned short)(p - 1)
                                     : (unsigned short)0xFFFF;
    }
    lvl[lt] = 1;
    myl[k] = 1;
  }
  __syncthreads();

  // monotone Jacobi relaxation to the unique longest-path fixpoint
  for (int pass = 0; pass < 128; ++pass) {
    if (tid == 0) chg = 0;
    __syncthreads();
    bool ch = false;
#pragma unroll
    for (int k = 0; k < 4; ++k) {
      int m = 0;
#pragma unroll
      for (int j = 0; j < 8; ++j) {
        const unsigned short p = pred[k][j];
        if (p != 0xFFFF) m = max(m, (int)lvl[p]);
      }
      const int nl = m + 1;  // levels only grow
      if (nl != myl[k]) {
        myl[k] = nl;
        lvl[tid + k * 1024] = (unsigned short)nl;
        ch = true;
      }
    }
    if (ch) chg = 1;
    __syncthreads();
    if (chg == 0) break;  // full no-change pass == converged
  }

#pragma unroll
  for (int k = 0; k < 4; ++k) atomicMax(&bmax, myl[k]);
  __syncthreads();
  const int vmax = bmax;

#pragma unroll
  for (int k = 0; k < 4; ++k) (void)agg_pos(myl[k], cnt, vmax);  // histogram
  __syncthreads();
  if (tid == 0) {
    int e = 0;
    for (int r = 0; r < RMAX; ++r) {  // cnt[0]==0
      coff[r] = e;
      e += cnt[r];
      ends[w * RMAX + r] = e;  // cumulative end through round r
    }
  }
  __syncthreads();

#pragma unroll
  for (int k = 0; k < 4; ++k) {
    const int pos = agg_pos(myl[k], coff, vmax);
    const int lt = tid + k * 1024;
    const int gp = wbase + pos;
    recpk[gp] = make_uint2((unsigned)uvk[k],
                           __float_as_uint(uni[wbase + lt]));          // sweep 0
    recpk[NSITES + gp] = make_uint2((unsigned)uvk[k],
                                    __float_as_uint(uni[NSITES + wbase + lt]));
  }
}

// ---------------------------------------------------------------------------
// Kernel B: executor — 1 block x 1024 threads.
// Records register-resident (4 x uint2/thread, double-buffered across windows).
// R1 body restored (phase-split regressed: issue-bound, not LDS-latency-bound).
// NEW this round:
//  (1) round bounds forced into SGPRs via readfirstlane; k-block overlap test
//      is a scalar branch; fully-covered k-blocks run unguarded.
//  (2) tail mode: once a round has <=64 records, wave 0 finishes the window's
//      remaining rounds alone (per-wave in-order DS pipe replaces barriers),
//      re-reading records from L2-resident recpk with 1-round lookahead.
// ---------------------------------------------------------------------------
__device__ __forceinline__ void do_update(unsigned char* cell,
                                          const unsigned int* cellw,
                                          const float4* ctab, unsigned uvv,
                                          float r) {
  const int u = uvv >> 8, v = (int)(uvv & 255u);
  const int um = u ? u - 1 : 0, up = u < 255 ? u + 1 : 255;
  const int vm = v ? v - 1 : 0, vp = v < 255 ? v + 1 : 255;
  const int cb = vm >> 2;              // dword col of 8-byte window start
  const int sh0 = (vm & 3) << 3;
  const int shv = (v - vm) << 3;       // 0 or 8
  const int shp = (vp - vm) << 3;      // 8 or 16 (or 8 at right border)
  int acc = 0;  // per-class counts in nibbles (class 4 -> bit16, unused)
  {  // top row: cols vm, v, vp (clipped dups included, matching reference)
    const unsigned int* rw = cellw + (um << 6) + cb;
    const unsigned long long wd =
        ((unsigned long long)rw[1] << 32) | (unsigned long long)rw[0];
    const unsigned wl = (unsigned)(wd >> sh0);
    acc += 1 << ((wl & 255u) << 2);
    acc += 1 << (((wl >> shv) & 255u) << 2);
    acc += 1 << (((wl >> shp) & 255u) << 2);
  }
  {  // middle row: cols vm, vp only (true center excluded exactly once)
    const unsigned int* rw = cellw + (u << 6) + cb;
    const unsigned long long wd =
        ((unsigned long long)rw[1] << 32) | (unsigned long long)rw[0];
    const unsigned wl = (unsigned)(wd >> sh0);
    acc += 1 << ((wl & 255u) << 2);
    acc += 1 << (((wl >> shp) & 255u) << 2);
  }
  {  // bottom row: cols vm, v, vp
    const unsigned int* rw = cellw + (up << 6) + cb;
    const unsigned long long wd =
        ((unsigned long long)rw[1] << 32) | (unsigned long long)rw[0];
    const unsigned wl = (unsigned)(wd >> sh0);
    acc += 1 << ((wl & 255u) << 2);
    acc += 1 << (((wl >> shv) & 255u) << 2);
    acc += 1 << (((wl >> shp) & 255u) << 2);
  }
  const int n0 = acc & 15, n1 = (acc >> 4) & 15, n2 = (acc >> 8) & 15;
  const float4 c = ctab[n0 + 9 * n1 + 81 * n2];
  int cnt = (c.x < r) ? 1 : 0;
  cnt += (c.y < r) ? 1 : 0;
  cnt += (c.z < r) ? 1 : 0;
  cnt += (c.w < r) ? 1 : 0;
  cell[uvv] = (unsigned char)cnt;  // 0..4
}

// Execute all rounds of one window. R register-resident (const-indexed only).
// rp = this window's record stream in global (for tail mode re-reads).
__device__ __forceinline__ void run_rounds(unsigned char* cell,
                                           const unsigned int* cellw,
                                           const float4* ctab, const int* le,
                                           const uint2 (&R)[4], int tid,
                                           const uint2* __restrict__ rp) {
  const int wave = tid >> 6, lane = tid & 63;
  int b = 0;
  int e = __builtin_amdgcn_readfirstlane(le[1]);
  for (int rd = 1; rd < RMAX; ++rd) {
    if (b >= WIN) break;  // uniform: window complete
    if (e - b <= 64) {
      // ---- tail mode: wave 0 finishes the window, no more barriers ----
      if (wave == 0) {
        int tb = b, te = e, trd = rd;
        uint2 cur = make_uint2(0u, 0u);
        if (tb + lane < te) cur = rp[tb + lane];
        while (tb < WIN) {
          const int tnb = te;
          const int tne = (trd + 1 < RMAX)
                              ? __builtin_amdgcn_readfirstlane(le[trd + 1])
                              : te;
          // lookahead: next round's records while current round computes
          uint2 nxt = make_uint2(0u, 0u);
          if (tnb + lane < tne) nxt = rp[tnb + lane];
          if (tb + lane < te)
            do_update(cell, cellw, ctab, cur.x, __uint_as_float(cur.y));
          for (int s = tb + lane + 64; s < te; s += 64) {  // safety: >64 recs
            const uint2 rc = rp[s];
            do_update(cell, cellw, ctab, rc.x, __uint_as_float(rc.y));
          }
          cur = nxt;
          tb = tnb;
          te = tne;
          ++trd;
        }
      }
      __syncthreads();  // window-end: tail writes visible to all waves
      return;
    }
    // ---- wide round: all waves, scalar-guarded k-blocks ----
    const int nb = e;
    const int ne = (rd + 1 < RMAX)
                       ? __builtin_amdgcn_readfirstlane(le[rd + 1])
                       : e;
#pragma unroll
    for (int k = 0; k < 4; ++k) {
      const int kb = k << 10;
      if (e > kb && b < kb + 1024) {        // scalar: block overlaps round
        if (b <= kb && kb + 1024 <= e) {    // scalar: fully covered
          do_update(cell, cellw, ctab, R[k].x, __uint_as_float(R[k].y));
        } else {
          const int s = tid + kb;
          if (s >= b && s < e)
            do_update(cell, cellw, ctab, R[k].x, __uint_as_float(R[k].y));
        }
      }
    }
    __syncthreads();  // round rd writes before round rd+1 reads
    b = nb;
    e = ne;
  }
}

__global__ __launch_bounds__(1024) void GibbsSampler_90443421319469_kernel(
    const int* __restrict__ Xi, const uint2* __restrict__ recpk,
    const float* __restrict__ betap, const int* __restrict__ ends,
    int* __restrict__ out) {
#pragma clang fp contract(off)
  __shared__ __align__(16) unsigned int cellw[NSITES / 4];  // 64 KiB lattice
  __shared__ float4 ctab[732];                              // 11.7 KiB
  __shared__ int lend[NW * RMAX];                           // 4 KiB
  unsigned char* cell = (unsigned char*)cellw;
  const int tid = threadIdx.x;
  const float beta = betap[0];

  // issue window-0 record loads first so HBM latency hides under LDS init
  uint2 ra[4], rb[4];
#pragma unroll
  for (int k = 0; k < 4; ++k) ra[k] = recpk[tid + (k << 10)];

  for (int g = tid; g < NSITES / 4; g += 1024) {
    int4 x = ((const int4*)Xi)[g];
    // pack 4 int32 cells into one dword (byte lanes)
    cellw[g] = (unsigned)(x.x & 255) | ((unsigned)(x.y & 255) << 8) |
               ((unsigned)(x.z & 255) << 16) | ((unsigned)(x.w & 255) << 24);
  }
  lend[tid] = ends[tid];  // NW*RMAX == 1024
  // cumulative softmax table: bit-identical to per-update reference math
  for (int t = tid; t < 729; t += 1024) {
    const int n0 = t % 9, n1 = (t / 9) % 9, n2 = t / 81;
    const int n3 = 8 - n0 - n1 - n2;
    float4 val = make_float4(2.f, 2.f, 2.f, 2.f);  // unreachable combos
    if (n3 >= 0) {
      const int mx = max(max(n0, n1), max(n2, n3));
      const float xm = beta * (float)mx;   // fl(beta*mx), no FMA (contract off)
      const float x0 = beta * (float)n0;
      const float x1 = beta * (float)n1;
      const float x2 = beta * (float)n2;
      const float x3 = beta * (float)n3;
      const float e0 = (float)exp((double)(x0 - xm));
      const float e1 = (float)exp((double)(x1 - xm));
      const float e2 = (float)exp((double)(x2 - xm));
      const float e3 = (float)exp((double)(x3 - xm));
      const float s = ((e0 + e1) + e2) + e3;  // sequential sum, like np/XLA
      const float c0 = e0 / s;                // IEEE f32 divides, like ref
      const float c1 = c0 + e1 / s;
      const float c2 = c1 + e2 / s;
      const float c3 = c2 + e3 / s;
      val = make_float4(c0, c1, c2, c3);
    }
    ctab[t] = val;
  }
  __syncthreads();

  for (int w = 0; w < 2 * NW; ++w) {
    const int ww = w & (NW - 1);
    const int* le = &lend[ww * RMAX];
    const uint2* rpc = recpk + (w >> 4) * NSITES + ww * WIN;  // current window
    const int wn = w + 1;  // prefetch target (guarded; pointer calc only)
    const uint2* rpn = recpk + (wn >> 4) * NSITES + (wn & (NW - 1)) * WIN;
    if ((w & 1) == 0) {
      if (wn < 2 * NW) {
#pragma unroll
        for (int k = 0; k < 4; ++k) rb[k] = rpn[tid + (k << 10)];
      }
      run_rounds(cell, cellw, ctab, le, ra, tid, rpc);
    } else {
      if (wn < 2 * NW) {
#pragma unroll
        for (int k = 0; k < 4; ++k) ra[k] = rpn[tid + (k << 10)];
      }
      run_rounds(cell, cellw, ctab, le, rb, tid, rpc);
    }
  }

  for (int g = tid; g < NSITES / 4; g += 1024) {
    const unsigned p = cellw[g];
    int4 o;
    o.x = (int)(p & 255u);
    o.y = (int)((p >> 8) & 255u);
    o.z = (int)((p >> 16) & 255u);
    o.w = (int)((p >> 24) & 255u);
    ((int4*)out)[g] = o;
  }
}

extern "C" void kernel_launch(void* const* d_in, const int* in_sizes, int n_in,
                              void* d_out, int out_size, void* d_ws,
                              size_t ws_size, hipStream_t stream) {
  const int* Xi = (const int*)d_in[0];
  const int* perm = (const int*)d_in[1];
  const float* uni = (const float*)d_in[2];
  const float* beta = (const float*)d_in[3];
  int* out = (int*)d_out;

  char* ws = (char*)d_ws;
  uint2* recpk = (uint2*)ws;                 // 1 MiB
  int* ends = (int*)(ws + 2 * NSITES * 8);   // 4 KiB

  GibbsSched_kernel<<<dim3(NW), dim3(1024), 0, stream>>>(perm, uni, recpk,
                                                         ends);
  GibbsSampler_90443421319469_kernel<<<dim3(1), dim3(1024), 0, stream>>>(
      Xi, recpk, beta, ends, out);
}

// Round 4
// 225.010 us; speedup vs baseline: 1.0382x; 1.0231x over previous
//
#include <hip/hip_runtime.h>
#include <math.h>

#define NSITES 65536
#define WIN 4096
#define NW 16          // windows per sweep
#define RMAX 64        // tracked rounds per window (observed depth ~7)

// ws layout:
//   recpk  uint2[2*NSITES]   1048576 B  ({site, uniform-bits} per sorted slot, per sweep)
//   ends   int  [NW*RMAX]       4096 B  (cumulative round boundaries, per window)

// wave-aggregated atomic rank: position for value v in counter array c
// (1-based values, v <= vmax; vmax wave-uniform).
__device__ __forceinline__ int agg_pos(int v, int* c, int vmax) {
  int pos = 0;
  const int lane = threadIdx.x & 63;
  for (int vv = 1; vv <= vmax; ++vv) {
    unsigned long long m = __ballot(v == vv);
    if (m) {
      int leader = __ffsll((long long)m) - 1;
      int base = 0;
      if (lane == leader) base = atomicAdd(&c[vv], (int)__popcll(m));
      base = __shfl(base, leader);
      if (v == vv) pos = base + (int)__popcll(m & ((1ull << lane) - 1ull));
    }
  }
  return pos;
}

// ---------------------------------------------------------------------------
// Kernel A: per-window DAG leveling + counting sort + packed record gather.
// One 1024-thread block per window; window-local position grid in LDS.
// (UNCHANGED — single-variable discipline.)
// ---------------------------------------------------------------------------
__global__ __launch_bounds__(1024) void GibbsSched_kernel(
    const int* __restrict__ perm, const float* __restrict__ uni,
    uint2* __restrict__ recpk, int* __restrict__ ends) {
  __shared__ unsigned short posg[NSITES];  // 128 KiB: local pos+1, 0 = absent
  __shared__ unsigned short lvl[WIN];      // 8 KiB
  __shared__ int cnt[RMAX + 1], coff[RMAX + 1];
  __shared__ int chg, bmax;
  const int tid = threadIdx.x;
  const int w = blockIdx.x;
  const int wbase = w * WIN;

  for (int g = tid; g < NSITES / 8; g += 1024)  // 8 ushorts per uint4
    ((uint4*)posg)[g] = make_uint4(0u, 0u, 0u, 0u);
  for (int i = tid; i <= RMAX; i += 1024) { cnt[i] = 0; coff[i] = 0; }
  if (tid == 0) bmax = 0;
  __syncthreads();

  int uvk[4];
#pragma unroll
  for (int k = 0; k < 4; ++k) {
    const int lt = tid + k * 1024;
    uvk[k] = perm[wbase + lt];
    posg[uvk[k]] = (unsigned short)(lt + 1);  // sites unique within a sweep
  }
  __syncthreads();

  unsigned short pred[4][8];
  int myl[4];
#pragma unroll
  for (int k = 0; k < 4; ++k) {
    const int lt = tid + k * 1024;
    const int uv = uvk[k], u = uv >> 8, v = uv & 255;
    const int um = u ? u - 1 : 0, up = u < 255 ? u + 1 : 255;
    const int vm = v ? v - 1 : 0, vp = v < 255 ? v + 1 : 255;
    const int nb8[8] = {(um << 8) | vm, (um << 8) | v, (um << 8) | vp,
                        (u << 8) | vm,                 (u << 8) | vp,
                        (up << 8) | vm, (up << 8) | v, (up << 8) | vp};
#pragma unroll
    for (int j = 0; j < 8; ++j) {
      const int p = posg[nb8[j]];  // clipped dup == self -> p-1==lt, excluded
      pred[k][j] = (p && p - 1 < lt) ? (unsigned short)(p - 1)
                                     : (unsigned short)0xFFFF;
    }
    lvl[lt] = 1;
    myl[k] = 1;
  }
  __syncthreads();

  // monotone Jacobi relaxation to the unique longest-path fixpoint
  for (int pass = 0; pass < 128; ++pass) {
    if (tid == 0) chg = 0;
    __syncthreads();
    bool ch = false;
#pragma unroll
    for (int k = 0; k < 4; ++k) {
      int m = 0;
#pragma unroll
      for (int j = 0; j < 8; ++j) {
        const unsigned short p = pred[k][j];
        if (p != 0xFFFF) m = max(m, (int)lvl[p]);
      }
      const int nl = m + 1;  // levels only grow
      if (nl != myl[k]) {
        myl[k] = nl;
        lvl[tid + k * 1024] = (unsigned short)nl;
        ch = true;
      }
    }
    if (ch) chg = 1;
    __syncthreads();
    if (chg == 0) break;  // full no-change pass == converged
  }

#pragma unroll
  for (int k = 0; k < 4; ++k) atomicMax(&bmax, myl[k]);
  __syncthreads();
  const int vmax = bmax;

#pragma unroll
  for (int k = 0; k < 4; ++k) (void)agg_pos(myl[k], cnt, vmax);  // histogram
  __syncthreads();
  if (tid == 0) {
    int e = 0;
    for (int r = 0; r < RMAX; ++r) {  // cnt[0]==0
      coff[r] = e;
      e += cnt[r];
      ends[w * RMAX + r] = e;  // cumulative end through round r
    }
  }
  __syncthreads();

#pragma unroll
  for (int k = 0; k < 4; ++k) {
    const int pos = agg_pos(myl[k], coff, vmax);
    const int lt = tid + k * 1024;
    const int gp = wbase + pos;
    recpk[gp] = make_uint2((unsigned)uvk[k],
                           __float_as_uint(uni[wbase + lt]));          // sweep 0
    recpk[NSITES + gp] = make_uint2((unsigned)uvk[k],
                                    __float_as_uint(uni[NSITES + wbase + lt]));
  }
}

// ---------------------------------------------------------------------------
// Kernel B: executor — 1 block x 1024 threads. R1 structure restored
// (best measured: 124.5 us; R2's phase-split and R3's scalar-guard/tail-mode
// both regressed and are reverted).
// NEW this round: ctab stored SoA (4 x float[736]) instead of AoS float4.
// The AoS b128 gather had start-bank = (4*idx)%32 -> only 8 start groups ->
// forced ~8-way bank conflicts. SoA b32 gathers spread over all 32 banks
// (~2 lanes/bank = free). Same table values -> bit-identical output.
// ---------------------------------------------------------------------------
__device__ __forceinline__ void do_update(unsigned char* cell,
                                          const unsigned int* cellw,
                                          const float* ct0, const float* ct1,
                                          const float* ct2, const float* ct3,
                                          unsigned uvv, float r) {
  const int u = uvv >> 8, v = (int)(uvv & 255u);
  const int um = u ? u - 1 : 0, up = u < 255 ? u + 1 : 255;
  const int vm = v ? v - 1 : 0, vp = v < 255 ? v + 1 : 255;
  const int cb = vm >> 2;              // dword col of 8-byte window start
  const int sh0 = (vm & 3) << 3;
  const int shv = (v - vm) << 3;       // 0 or 8
  const int shp = (vp - vm) << 3;      // 8 or 16 (or 8 at right border)
  int acc = 0;  // per-class counts in nibbles (class 4 -> bit16, unused)
  {  // top row: cols vm, v, vp (clipped dups included, matching reference)
    const unsigned int* rw = cellw + (um << 6) + cb;
    const unsigned long long wd =
        ((unsigned long long)rw[1] << 32) | (unsigned long long)rw[0];
    const unsigned wl = (unsigned)(wd >> sh0);
    acc += 1 << ((wl & 255u) << 2);
    acc += 1 << (((wl >> shv) & 255u) << 2);
    acc += 1 << (((wl >> shp) & 255u) << 2);
  }
  {  // middle row: cols vm, vp only (true center excluded exactly once)
    const unsigned int* rw = cellw + (u << 6) + cb;
    const unsigned long long wd =
        ((unsigned long long)rw[1] << 32) | (unsigned long long)rw[0];
    const unsigned wl = (unsigned)(wd >> sh0);
    acc += 1 << ((wl & 255u) << 2);
    acc += 1 << (((wl >> shp) & 255u) << 2);
  }
  {  // bottom row: cols vm, v, vp
    const unsigned int* rw = cellw + (up << 6) + cb;
    const unsigned long long wd =
        ((unsigned long long)rw[1] << 32) | (unsigned long long)rw[0];
    const unsigned wl = (unsigned)(wd >> sh0);
    acc += 1 << ((wl & 255u) << 2);
    acc += 1 << (((wl >> shv) & 255u) << 2);
    acc += 1 << (((wl >> shp) & 255u) << 2);
  }
  const int n0 = acc & 15, n1 = (acc >> 4) & 15, n2 = (acc >> 8) & 15;
  const int idx = n0 + 9 * n1 + 81 * n2;
  const float c0 = ct0[idx];
  const float c1 = ct1[idx];
  const float c2 = ct2[idx];
  const float c3 = ct3[idx];
  int cnt = (c0 < r) ? 1 : 0;
  cnt += (c1 < r) ? 1 : 0;
  cnt += (c2 < r) ? 1 : 0;
  cnt += (c3 < r) ? 1 : 0;
  cell[uvv] = (unsigned char)cnt;  // 0..4
}

// Execute all rounds of one window from a register-resident record set.
// R is indexed only by compile-time constants -> stays in VGPRs (rule #20).
__device__ __forceinline__ void run_rounds(unsigned char* cell,
                                           const unsigned int* cellw,
                                           const float* ct0, const float* ct1,
                                           const float* ct2, const float* ct3,
                                           const int* le, const uint2 (&R)[4],
                                           int tid) {
  int b = 0, e = le[1];
  for (int rd = 1; rd < RMAX; ++rd) {
    if (b >= WIN) break;  // uniform: window complete
    // pipeline: fetch next round's bounds before the barrier
    const int nb = e;
    const int ne = (rd + 1 < RMAX) ? le[rd + 1] : e;
#pragma unroll
    for (int k = 0; k < 4; ++k) {
      const int s = tid + (k << 10);
      if (s >= b && s < e)
        do_update(cell, cellw, ct0, ct1, ct2, ct3, R[k].x,
                  __uint_as_float(R[k].y));
    }
    __syncthreads();  // round rd writes before round rd+1 reads
    b = nb;
    e = ne;
  }
}

__global__ __launch_bounds__(1024) void GibbsSampler_90443421319469_kernel(
    const int* __restrict__ Xi, const uint2* __restrict__ recpk,
    const float* __restrict__ betap, const int* __restrict__ ends,
    int* __restrict__ out) {
#pragma clang fp contract(off)
  __shared__ __align__(16) unsigned int cellw[NSITES / 4];  // 64 KiB lattice
  __shared__ float ct0[736], ct1[736], ct2[736], ct3[736];  // 11.5 KiB SoA
  __shared__ int lend[NW * RMAX];                           // 4 KiB
  unsigned char* cell = (unsigned char*)cellw;
  const int tid = threadIdx.x;
  const float beta = betap[0];

  // issue window-0 record loads first so HBM latency hides under LDS init
  uint2 ra[4], rb[4];
#pragma unroll
  for (int k = 0; k < 4; ++k) ra[k] = recpk[tid + (k << 10)];

  for (int g = tid; g < NSITES / 4; g += 1024) {
    int4 x = ((const int4*)Xi)[g];
    // pack 4 int32 cells into one dword (byte lanes)
    cellw[g] = (unsigned)(x.x & 255) | ((unsigned)(x.y & 255) << 8) |
               ((unsigned)(x.z & 255) << 16) | ((unsigned)(x.w & 255) << 24);
  }
  lend[tid] = ends[tid];  // NW*RMAX == 1024
  // cumulative softmax table: bit-identical to per-update reference math
  for (int t = tid; t < 729; t += 1024) {
    const int n0 = t % 9, n1 = (t / 9) % 9, n2 = t / 81;
    const int n3 = 8 - n0 - n1 - n2;
    float4 val = make_float4(2.f, 2.f, 2.f, 2.f);  // unreachable combos
    if (n3 >= 0) {
      const int mx = max(max(n0, n1), max(n2, n3));
      const float xm = beta * (float)mx;   // fl(beta*mx), no FMA (contract off)
      const float x0 = beta * (float)n0;
      const float x1 = beta * (float)n1;
      const float x2 = beta * (float)n2;
      const float x3 = beta * (float)n3;
      const float e0 = (float)exp((double)(x0 - xm));
      const float e1 = (float)exp((double)(x1 - xm));
      const float e2 = (float)exp((double)(x2 - xm));
      const float e3 = (float)exp((double)(x3 - xm));
      const float s = ((e0 + e1) + e2) + e3;  // sequential sum, like np/XLA
      const float c0 = e0 / s;                // IEEE f32 divides, like ref
      const float c1 = c0 + e1 / s;
      const float c2 = c1 + e2 / s;
      const float c3 = c2 + e3 / s;
      val = make_float4(c0, c1, c2, c3);
    }
    ct0[t] = val.x;
    ct1[t] = val.y;
    ct2[t] = val.z;
    ct3[t] = val.w;
  }
  __syncthreads();

  for (int w = 0; w < 2 * NW; ++w) {
    const int ww = w & (NW - 1);
    const int* le = &lend[ww * RMAX];
    const int wn = w + 1;  // prefetch target (guarded; pointer calc only)
    const uint2* rpn = recpk + (wn >> 4) * NSITES + (wn & (NW - 1)) * WIN;
    if ((w & 1) == 0) {
      if (wn < 2 * NW) {
#pragma unroll
        for (int k = 0; k < 4; ++k) rb[k] = rpn[tid + (k << 10)];
      }
      run_rounds(cell, cellw, ct0, ct1, ct2, ct3, le, ra, tid);
    } else {
      if (wn < 2 * NW) {
#pragma unroll
        for (int k = 0; k < 4; ++k) ra[k] = rpn[tid + (k << 10)];
      }
      run_rounds(cell, cellw, ct0, ct1, ct2, ct3, le, rb, tid);
    }
  }

  for (int g = tid; g < NSITES / 4; g += 1024) {
    const unsigned p = cellw[g];
    int4 o;
    o.x = (int)(p & 255u);
    o.y = (int)((p >> 8) & 255u);
    o.z = (int)((p >> 16) & 255u);
    o.w = (int)((p >> 24) & 255u);
    ((int4*)out)[g] = o;
  }
}

extern "C" void kernel_launch(void* const* d_in, const int* in_sizes, int n_in,
                              void* d_out, int out_size, void* d_ws,
                              size_t ws_size, hipStream_t stream) {
  const int* Xi = (const int*)d_in[0];
  const int* perm = (const int*)d_in[1];
  const float* uni = (const float*)d_in[2];
  const float* beta = (const float*)d_in[3];
  int* out = (int*)d_out;

  char* ws = (char*)d_ws;
  uint2* recpk = (uint2*)ws;                 // 1 MiB
  int* ends = (int*)(ws + 2 * NSITES * 8);   // 4 KiB

  GibbsSched_kernel<<<dim3(NW), dim3(1024), 0, stream>>>(perm, uni, recpk,
                                                         ends);
  GibbsSampler_90443421319469_kernel<<<dim3(1), dim3(1024), 0, stream>>>(
      Xi, recpk, beta, ends, out);
}

// Round 5
// 215.874 us; speedup vs baseline: 1.0822x; 1.0423x over previous
//
#include <hip/hip_runtime.h>
#include <math.h>

#define NSITES 65536
#define WIN 4096
#define NW 16          // windows per sweep
#define RMAX 32        // tracked rounds per window (observed depth ~7, fixed seed)

// ws layout:
//   recpk  uint2[2*NSITES]   1048576 B  ({site, uniform-bits} per sorted slot, per sweep)
//   ends   int  [NW*RMAX]       2048 B  (cumulative round boundaries, per window)
//   flag   int                     4 B  (A-phase completion count, memset to 0 per run)

// wave-aggregated atomic rank: position for value v in counter array c
// (1-based values, v <= vmax; vmax wave-uniform).
__device__ __forceinline__ int agg_pos(int v, int* c, int vmax) {
  int pos = 0;
  const int lane = threadIdx.x & 63;
  for (int vv = 1; vv <= vmax; ++vv) {
    unsigned long long m = __ballot(v == vv);
    if (m) {
      int leader = __ffsll((long long)m) - 1;
      int base = 0;
      if (lane == leader) base = atomicAdd(&c[vv], (int)__popcll(m));
      base = __shfl(base, leader);
      if (v == vv) pos = base + (int)__popcll(m & ((1ull << lane) - 1ull));
    }
  }
  return pos;
}

// B-phase per-update: 3 row-window LDS reads (2 dwords each) -> neighbor
// histogram -> one float4 ctab read -> 4 compares -> byte write. (R1 body,
// best measured; SoA/phase-split/tail variants all regressed and are reverted.)
__device__ __forceinline__ void do_update(unsigned char* cell,
                                          const unsigned int* cellw,
                                          const float4* ctab, unsigned uvv,
                                          float r) {
  const int u = uvv >> 8, v = (int)(uvv & 255u);
  const int um = u ? u - 1 : 0, up = u < 255 ? u + 1 : 255;
  const int vm = v ? v - 1 : 0, vp = v < 255 ? v + 1 : 255;
  const int cb = vm >> 2;              // dword col of 8-byte window start
  const int sh0 = (vm & 3) << 3;
  const int shv = (v - vm) << 3;       // 0 or 8
  const int shp = (vp - vm) << 3;      // 8 or 16 (or 8 at right border)
  int acc = 0;  // per-class counts in nibbles (class 4 -> bit16, unused)
  {  // top row: cols vm, v, vp (clipped dups included, matching reference)
    const unsigned int* rw = cellw + (um << 6) + cb;
    const unsigned long long wd =
        ((unsigned long long)rw[1] << 32) | (unsigned long long)rw[0];
    const unsigned wl = (unsigned)(wd >> sh0);
    acc += 1 << ((wl & 255u) << 2);
    acc += 1 << (((wl >> shv) & 255u) << 2);
    acc += 1 << (((wl >> shp) & 255u) << 2);
  }
  {  // middle row: cols vm, vp only (true center excluded exactly once)
    const unsigned int* rw = cellw + (u << 6) + cb;
    const unsigned long long wd =
        ((unsigned long long)rw[1] << 32) | (unsigned long long)rw[0];
    const unsigned wl = (unsigned)(wd >> sh0);
    acc += 1 << ((wl & 255u) << 2);
    acc += 1 << (((wl >> shp) & 255u) << 2);
  }
  {  // bottom row: cols vm, v, vp
    const unsigned int* rw = cellw + (up << 6) + cb;
    const unsigned long long wd =
        ((unsigned long long)rw[1] << 32) | (unsigned long long)rw[0];
    const unsigned wl = (unsigned)(wd >> sh0);
    acc += 1 << ((wl & 255u) << 2);
    acc += 1 << (((wl >> shv) & 255u) << 2);
    acc += 1 << (((wl >> shp) & 255u) << 2);
  }
  const int n0 = acc & 15, n1 = (acc >> 4) & 15, n2 = (acc >> 8) & 15;
  const float4 c = ctab[n0 + 9 * n1 + 81 * n2];
  int cnt = (c.x < r) ? 1 : 0;
  cnt += (c.y < r) ? 1 : 0;
  cnt += (c.z < r) ? 1 : 0;
  cnt += (c.w < r) ? 1 : 0;
  cell[uvv] = (unsigned char)cnt;  // 0..4
}

// Execute all rounds of one window from a register-resident record set.
// R is indexed only by compile-time constants -> stays in VGPRs.
__device__ __forceinline__ void run_rounds(unsigned char* cell,
                                           const unsigned int* cellw,
                                           const float4* ctab, const int* le,
                                           const uint2 (&R)[4], int tid) {
  int b = 0, e = le[1];
  for (int rd = 1; rd < RMAX; ++rd) {
    if (b >= WIN) break;  // uniform: window complete
    // pipeline: fetch next round's bounds before the barrier
    const int nb = e;
    const int ne = (rd + 1 < RMAX) ? le[rd + 1] : e;
#pragma unroll
    for (int k = 0; k < 4; ++k) {
      const int s = tid + (k << 10);
      if (s >= b && s < e)
        do_update(cell, cellw, ctab, R[k].x, __uint_as_float(R[k].y));
    }
    __syncthreads();  // round rd writes before round rd+1 reads
    b = nb;
    e = ne;
  }
}

// ---------------------------------------------------------------------------
// FUSED kernel: 16 blocks x 1024 threads.
// All blocks: A-phase (DAG leveling + counting sort + record gather for their
// window) -> device-scope release + flag signal. Blocks 1..15 exit.
// Block 0: spin-acquire until 15 peers signaled, then B-phase (R1 executor).
// LDS is an overlay union: A-phase 139.5 KiB, B-phase 79.3 KiB.
// ---------------------------------------------------------------------------
__global__ __launch_bounds__(1024) void GibbsSampler_90443421319469_kernel(
    const int* __restrict__ Xi, const int* __restrict__ perm,
    const float* __restrict__ uni, const float* __restrict__ betap,
    uint2* __restrict__ recpk, int* __restrict__ ends,
    int* __restrict__ flag, int* __restrict__ out) {
#pragma clang fp contract(off)
  __shared__ __align__(16) unsigned char smem[139552];
  // ---- A-phase overlay ----
  unsigned short* posg = (unsigned short*)smem;            // 131072 B
  unsigned short* lvl = (unsigned short*)(smem + 131072);  //   8192 B
  int* cnt = (int*)(smem + 139264);                        //    132 B
  int* coff = (int*)(smem + 139396);                       //    132 B
  int* chg = (int*)(smem + 139528);
  int* bmax = (int*)(smem + 139532);
  // ---- B-phase overlay ----
  unsigned int* cellw = (unsigned int*)smem;               //  65536 B
  float4* ctab = (float4*)(smem + 65536);                  //  11712 B
  int* lend = (int*)(smem + 77248);                        //   2048 B

  const int tid = threadIdx.x;
  const int w = blockIdx.x;
  const int wbase = w * WIN;

  // ======================= A-phase (all 16 blocks) =======================
  for (int g = tid; g < NSITES / 8; g += 1024)  // 8 ushorts per uint4
    ((uint4*)posg)[g] = make_uint4(0u, 0u, 0u, 0u);
  for (int i = tid; i <= RMAX; i += 1024) { cnt[i] = 0; coff[i] = 0; }
  if (tid == 0) *bmax = 0;
  __syncthreads();

  int uvk[4];
#pragma unroll
  for (int k = 0; k < 4; ++k) {
    const int lt = tid + k * 1024;
    uvk[k] = perm[wbase + lt];
    posg[uvk[k]] = (unsigned short)(lt + 1);  // sites unique within a sweep
  }
  __syncthreads();

  unsigned short pred[4][8];
  int myl[4];
#pragma unroll
  for (int k = 0; k < 4; ++k) {
    const int lt = tid + k * 1024;
    const int uv = uvk[k], u = uv >> 8, v = uv & 255;
    const int um = u ? u - 1 : 0, up = u < 255 ? u + 1 : 255;
    const int vm = v ? v - 1 : 0, vp = v < 255 ? v + 1 : 255;
    const int nb8[8] = {(um << 8) | vm, (um << 8) | v, (um << 8) | vp,
                        (u << 8) | vm,                 (u << 8) | vp,
                        (up << 8) | vm, (up << 8) | v, (up << 8) | vp};
#pragma unroll
    for (int j = 0; j < 8; ++j) {
      const int p = posg[nb8[j]];  // clipped dup == self -> p-1==lt, excluded
      pred[k][j] = (p && p - 1 < lt) ? (unsigned short)(p - 1)
                                     : (unsigned short)0xFFFF;
    }
    lvl[lt] = 1;
    myl[k] = 1;
  }
  __syncthreads();

  // monotone Jacobi relaxation to the unique longest-path fixpoint
  for (int pass = 0; pass < 128; ++pass) {
    if (tid == 0) *chg = 0;
    __syncthreads();
    bool ch = false;
#pragma unroll
    for (int k = 0; k < 4; ++k) {
      int m = 0;
#pragma unroll
      for (int j = 0; j < 8; ++j) {
        const unsigned short p = pred[k][j];
        if (p != 0xFFFF) m = max(m, (int)lvl[p]);
      }
      const int nl = m + 1;  // levels only grow
      if (nl != myl[k]) {
        myl[k] = nl;
        lvl[tid + k * 1024] = (unsigned short)nl;
        ch = true;
      }
    }
    if (ch) *chg = 1;
    __syncthreads();
    if (*chg == 0) break;  // full no-change pass == converged
  }

#pragma unroll
  for (int k = 0; k < 4; ++k) atomicMax(bmax, myl[k]);
  __syncthreads();
  const int vmax = *bmax;

#pragma unroll
  for (int k = 0; k < 4; ++k) (void)agg_pos(myl[k], cnt, vmax);  // histogram
  __syncthreads();
  if (tid == 0) {
    int e = 0;
    for (int r = 0; r < RMAX; ++r) {  // cnt[0]==0
      coff[r] = e;
      e += cnt[r];
      ends[w * RMAX + r] = e;  // cumulative end through round r
    }
  }
  __syncthreads();

#pragma unroll
  for (int k = 0; k < 4; ++k) {
    const int pos = agg_pos(myl[k], coff, vmax);
    const int lt = tid + k * 1024;
    const int gp = wbase + pos;
    recpk[gp] = make_uint2((unsigned)uvk[k],
                           __float_as_uint(uni[wbase + lt]));          // sweep 0
    recpk[NSITES + gp] = make_uint2((unsigned)uvk[k],
                                    __float_as_uint(uni[NSITES + wbase + lt]));
  }
  __syncthreads();  // every wave drained its own vmcnt -> block stores complete

  if (w != 0) {
    if (tid == 0) {
      __threadfence();         // device-scope release (L2 writeback)
      atomicAdd(flag, 1);      // device-scope by default
    }
    return;
  }

  // ===================== B-phase (block 0 only) =====================
  if (tid == 0) {
    while (__hip_atomic_load(flag, __ATOMIC_RELAXED,
                             __HIP_MEMORY_SCOPE_AGENT) < NW - 1)
      __builtin_amdgcn_s_sleep(2);
    __threadfence();           // device-scope acquire (cache invalidate)
  }
  __syncthreads();

  unsigned char* cell = (unsigned char*)cellw;
  const float beta = betap[0];

  // issue window-0 record loads first so HBM latency hides under LDS init
  uint2 ra[4], rb[4];
#pragma unroll
  for (int k = 0; k < 4; ++k) ra[k] = recpk[tid + (k << 10)];

  for (int g = tid; g < NSITES / 4; g += 1024) {
    int4 x = ((const int4*)Xi)[g];
    // pack 4 int32 cells into one dword (byte lanes)
    cellw[g] = (unsigned)(x.x & 255) | ((unsigned)(x.y & 255) << 8) |
               ((unsigned)(x.z & 255) << 16) | ((unsigned)(x.w & 255) << 24);
  }
  if (tid < NW * RMAX) lend[tid] = ends[tid];  // NW*RMAX == 512
  // cumulative softmax table: bit-identical to per-update reference math
  for (int t = tid; t < 729; t += 1024) {
    const int n0 = t % 9, n1 = (t / 9) % 9, n2 = t / 81;
    const int n3 = 8 - n0 - n1 - n2;
    float4 val = make_float4(2.f, 2.f, 2.f, 2.f);  // unreachable combos
    if (n3 >= 0) {
      const int mx = max(max(n0, n1), max(n2, n3));
      const float xm = beta * (float)mx;   // fl(beta*mx), no FMA (contract off)
      const float x0 = beta * (float)n0;
      const float x1 = beta * (float)n1;
      const float x2 = beta * (float)n2;
      const float x3 = beta * (float)n3;
      const float e0 = (float)exp((double)(x0 - xm));
      const float e1 = (float)exp((double)(x1 - xm));
      const float e2 = (float)exp((double)(x2 - xm));
      const float e3 = (float)exp((double)(x3 - xm));
      const float s = ((e0 + e1) + e2) + e3;  // sequential sum, like np/XLA
      const float c0 = e0 / s;                // IEEE f32 divides, like ref
      const float c1 = c0 + e1 / s;
      const float c2 = c1 + e2 / s;
      const float c3 = c2 + e3 / s;
      val = make_float4(c0, c1, c2, c3);
    }
    ctab[t] = val;
  }
  __syncthreads();

  for (int ww2 = 0; ww2 < 2 * NW; ++ww2) {
    const int ww = ww2 & (NW - 1);
    const int* le = &lend[ww * RMAX];
    const int wn = ww2 + 1;  // prefetch target (guarded; pointer calc only)
    const uint2* rpn = recpk + (wn >> 4) * NSITES + (wn & (NW - 1)) * WIN;
    if ((ww2 & 1) == 0) {
      if (wn < 2 * NW) {
#pragma unroll
        for (int k = 0; k < 4; ++k) rb[k] = rpn[tid + (k << 10)];
      }
      run_rounds(cell, cellw, ctab, le, ra, tid);
    } else {
      if (wn < 2 * NW) {
#pragma unroll
        for (int k = 0; k < 4; ++k) ra[k] = rpn[tid + (k << 10)];
      }
      run_rounds(cell, cellw, ctab, le, rb, tid);
    }
  }

  for (int g = tid; g < NSITES / 4; g += 1024) {
    const unsigned p = cellw[g];
    int4 o;
    o.x = (int)(p & 255u);
    o.y = (int)((p >> 8) & 255u);
    o.z = (int)((p >> 16) & 255u);
    o.w = (int)((p >> 24) & 255u);
    ((int4*)out)[g] = o;
  }
}

extern "C" void kernel_launch(void* const* d_in, const int* in_sizes, int n_in,
                              void* d_out, int out_size, void* d_ws,
                              size_t ws_size, hipStream_t stream) {
  const int* Xi = (const int*)d_in[0];
  const int* perm = (const int*)d_in[1];
  const float* uni = (const float*)d_in[2];
  const float* beta = (const float*)d_in[3];
  int* out = (int*)d_out;

  char* ws = (char*)d_ws;
  uint2* recpk = (uint2*)ws;                             // 1 MiB
  int* ends = (int*)(ws + 2 * NSITES * 8);               // 2048 B (RMAX=32)
  int* flag = (int*)(ws + 2 * NSITES * 8 + NW * RMAX * 4);  // 4 B

  hipMemsetAsync(flag, 0, sizeof(int), stream);  // graph-captured, per-replay
  GibbsSampler_90443421319469_kernel<<<dim3(NW), dim3(1024), 0, stream>>>(
      Xi, perm, uni, beta, recpk, ends, flag, out);
}

// Round 6
// 212.601 us; speedup vs baseline: 1.0988x; 1.0154x over previous
//
#include <hip/hip_runtime.h>
#include <math.h>

#define NSITES 65536
#define WIN 4096
#define NW 16          // windows per sweep
#define RMAX 32        // tracked rounds per window (observed depth ~7, fixed seed)

// ws layout:
//   recpk  uint2[2*NSITES]   1048576 B  ({site, uniform-bits} per sorted slot, per sweep)
//   ends   int  [NW*RMAX]       2048 B  (cumulative round boundaries, per window)
//   flag   int                     4 B  (A-phase completion count, memset to 0 per run)

// wave-aggregated atomic rank: position for value v in counter array c
// (1-based values, v <= vmax; vmax wave-uniform).
__device__ __forceinline__ int agg_pos(int v, int* c, int vmax) {
  int pos = 0;
  const int lane = threadIdx.x & 63;
  for (int vv = 1; vv <= vmax; ++vv) {
    unsigned long long m = __ballot(v == vv);
    if (m) {
      int leader = __ffsll((long long)m) - 1;
      int base = 0;
      if (lane == leader) base = atomicAdd(&c[vv], (int)__popcll(m));
      base = __shfl(base, leader);
      if (v == vv) pos = base + (int)__popcll(m & ((1ull << lane) - 1ull));
    }
  }
  return pos;
}

// B-phase per-update: 3 row-window LDS reads (2 dwords each) -> neighbor
// histogram -> one float4 ctab read -> 4 compares -> byte write. (R1 body,
// best measured; SoA/phase-split/tail variants all regressed and are reverted.)
__device__ __forceinline__ void do_update(unsigned char* cell,
                                          const unsigned int* cellw,
                                          const float4* ctab, unsigned uvv,
                                          float r) {
  const int u = uvv >> 8, v = (int)(uvv & 255u);
  const int um = u ? u - 1 : 0, up = u < 255 ? u + 1 : 255;
  const int vm = v ? v - 1 : 0, vp = v < 255 ? v + 1 : 255;
  const int cb = vm >> 2;              // dword col of 8-byte window start
  const int sh0 = (vm & 3) << 3;
  const int shv = (v - vm) << 3;       // 0 or 8
  const int shp = (vp - vm) << 3;      // 8 or 16 (or 8 at right border)
  int acc = 0;  // per-class counts in nibbles (class 4 -> bit16, unused)
  {  // top row: cols vm, v, vp (clipped dups included, matching reference)
    const unsigned int* rw = cellw + (um << 6) + cb;
    const unsigned long long wd =
        ((unsigned long long)rw[1] << 32) | (unsigned long long)rw[0];
    const unsigned wl = (unsigned)(wd >> sh0);
    acc += 1 << ((wl & 255u) << 2);
    acc += 1 << (((wl >> shv) & 255u) << 2);
    acc += 1 << (((wl >> shp) & 255u) << 2);
  }
  {  // middle row: cols vm, vp only (true center excluded exactly once)
    const unsigned int* rw = cellw + (u << 6) + cb;
    const unsigned long long wd =
        ((unsigned long long)rw[1] << 32) | (unsigned long long)rw[0];
    const unsigned wl = (unsigned)(wd >> sh0);
    acc += 1 << ((wl & 255u) << 2);
    acc += 1 << (((wl >> shp) & 255u) << 2);
  }
  {  // bottom row: cols vm, v, vp
    const unsigned int* rw = cellw + (up << 6) + cb;
    const unsigned long long wd =
        ((unsigned long long)rw[1] << 32) | (unsigned long long)rw[0];
    const unsigned wl = (unsigned)(wd >> sh0);
    acc += 1 << ((wl & 255u) << 2);
    acc += 1 << (((wl >> shv) & 255u) << 2);
    acc += 1 << (((wl >> shp) & 255u) << 2);
  }
  const int n0 = acc & 15, n1 = (acc >> 4) & 15, n2 = (acc >> 8) & 15;
  const float4 c = ctab[n0 + 9 * n1 + 81 * n2];
  int cnt = (c.x < r) ? 1 : 0;
  cnt += (c.y < r) ? 1 : 0;
  cnt += (c.z < r) ? 1 : 0;
  cnt += (c.w < r) ? 1 : 0;
  cell[uvv] = (unsigned char)cnt;  // 0..4
}

// Execute all rounds of one window from a register-resident record set.
// R is indexed only by compile-time constants -> stays in VGPRs.
__device__ __forceinline__ void run_rounds(unsigned char* cell,
                                           const unsigned int* cellw,
                                           const float4* ctab, const int* le,
                                           const uint2 (&R)[4], int tid) {
  int b = 0, e = le[1];
  for (int rd = 1; rd < RMAX; ++rd) {
    if (b >= WIN) break;  // uniform: window complete
    // pipeline: fetch next round's bounds before the barrier
    const int nb = e;
    const int ne = (rd + 1 < RMAX) ? le[rd + 1] : e;
#pragma unroll
    for (int k = 0; k < 4; ++k) {
      const int s = tid + (k << 10);
      if (s >= b && s < e)
        do_update(cell, cellw, ctab, R[k].x, __uint_as_float(R[k].y));
    }
    __syncthreads();  // round rd writes before round rd+1 reads
    b = nb;
    e = ne;
  }
}

// ---------------------------------------------------------------------------
// FUSED kernel: 16 blocks x 1024 threads.
// All blocks: A-phase -> device-scope release + flag signal; blocks 1..15 exit.
// Block 0: spin-acquire, then B-phase (R1 executor).
// NEW this round (A-phase only):
//  (1) synthetic pass 0: myl = has_pred ? 2 : 1 (== Jacobi pass-1 closed form,
//      min(true,2)) — zero LDS reads, replaces the one guaranteed-full pass.
//  (2) provable freeze: with monotone in-place updates, computed >= Jacobi ==
//      min(true, p+1) and computed <= true, so myl <= p after p passes implies
//      myl == true level -> skip its 8 pred reads forever (78% frozen after
//      p=1, 97.5% after p=2).
//  (3) one __syncthreads_count per pass replaces chg-flag + 2 barriers.
// ---------------------------------------------------------------------------
__global__ __launch_bounds__(1024) void GibbsSampler_90443421319469_kernel(
    const int* __restrict__ Xi, const int* __restrict__ perm,
    const float* __restrict__ uni, const float* __restrict__ betap,
    uint2* __restrict__ recpk, int* __restrict__ ends,
    int* __restrict__ flag, int* __restrict__ out) {
#pragma clang fp contract(off)
  __shared__ __align__(16) unsigned char smem[139552];
  // ---- A-phase overlay ----
  unsigned short* posg = (unsigned short*)smem;            // 131072 B
  unsigned short* lvl = (unsigned short*)(smem + 131072);  //   8192 B
  int* cnt = (int*)(smem + 139264);                        //    132 B
  int* coff = (int*)(smem + 139396);                       //    132 B
  int* bmax = (int*)(smem + 139532);
  // ---- B-phase overlay ----
  unsigned int* cellw = (unsigned int*)smem;               //  65536 B
  float4* ctab = (float4*)(smem + 65536);                  //  11712 B
  int* lend = (int*)(smem + 77248);                        //   2048 B

  const int tid = threadIdx.x;
  const int w = blockIdx.x;
  const int wbase = w * WIN;

  // ======================= A-phase (all 16 blocks) =======================
  for (int g = tid; g < NSITES / 8; g += 1024)  // 8 ushorts per uint4
    ((uint4*)posg)[g] = make_uint4(0u, 0u, 0u, 0u);
  for (int i = tid; i <= RMAX; i += 1024) { cnt[i] = 0; coff[i] = 0; }
  if (tid == 0) *bmax = 0;
  __syncthreads();

  int uvk[4];
#pragma unroll
  for (int k = 0; k < 4; ++k) {
    const int lt = tid + k * 1024;
    uvk[k] = perm[wbase + lt];
    posg[uvk[k]] = (unsigned short)(lt + 1);  // sites unique within a sweep
  }
  __syncthreads();

  unsigned short pred[4][8];
  int myl[4];
#pragma unroll
  for (int k = 0; k < 4; ++k) {
    const int lt = tid + k * 1024;
    const int uv = uvk[k], u = uv >> 8, v = uv & 255;
    const int um = u ? u - 1 : 0, up = u < 255 ? u + 1 : 255;
    const int vm = v ? v - 1 : 0, vp = v < 255 ? v + 1 : 255;
    const int nb8[8] = {(um << 8) | vm, (um << 8) | v, (um << 8) | vp,
                        (u << 8) | vm,                 (u << 8) | vp,
                        (up << 8) | vm, (up << 8) | v, (up << 8) | vp};
    bool hasp = false;
#pragma unroll
    for (int j = 0; j < 8; ++j) {
      const int p = posg[nb8[j]];  // clipped dup == self -> p-1==lt, excluded
      pred[k][j] = (p && p - 1 < lt) ? (unsigned short)(p - 1)
                                     : (unsigned short)0xFFFF;
      hasp |= (pred[k][j] != (unsigned short)0xFFFF);
    }
    // synthetic pass 0: Jacobi closed form min(true_level, 2)
    myl[k] = hasp ? 2 : 1;
    lvl[lt] = (unsigned short)myl[k];
  }
  __syncthreads();

  // monotone relaxation to the unique longest-path fixpoint, with freeze:
  // after p completed passes, myl <= p is provably final -> skip.
  for (int pass = 1; pass < 128; ++pass) {
    bool ch = false;
#pragma unroll
    for (int k = 0; k < 4; ++k) {
      if (myl[k] > pass) {  // not yet provably final
        int m = 0;
#pragma unroll
        for (int j = 0; j < 8; ++j) {
          const unsigned short p = pred[k][j];
          if (p != 0xFFFF) m = max(m, (int)lvl[p]);
        }
        const int nl = m + 1;  // levels only grow
        if (nl != myl[k]) {
          myl[k] = nl;
          lvl[tid + k * 1024] = (unsigned short)nl;
          ch = true;
        }
      }
    }
    if (__syncthreads_count((int)ch) == 0) break;  // no change == converged
  }

#pragma unroll
  for (int k = 0; k < 4; ++k) atomicMax(bmax, myl[k]);
  __syncthreads();
  const int vmax = *bmax;

#pragma unroll
  for (int k = 0; k < 4; ++k) (void)agg_pos(myl[k], cnt, vmax);  // histogram
  __syncthreads();
  if (tid == 0) {
    int e = 0;
    for (int r = 0; r < RMAX; ++r) {  // cnt[0]==0
      coff[r] = e;
      e += cnt[r];
      ends[w * RMAX + r] = e;  // cumulative end through round r
    }
  }
  __syncthreads();

#pragma unroll
  for (int k = 0; k < 4; ++k) {
    const int pos = agg_pos(myl[k], coff, vmax);
    const int lt = tid + k * 1024;
    const int gp = wbase + pos;
    recpk[gp] = make_uint2((unsigned)uvk[k],
                           __float_as_uint(uni[wbase + lt]));          // sweep 0
    recpk[NSITES + gp] = make_uint2((unsigned)uvk[k],
                                    __float_as_uint(uni[NSITES + wbase + lt]));
  }
  __syncthreads();  // every wave drained its own vmcnt -> block stores complete

  if (w != 0) {
    if (tid == 0) {
      __threadfence();         // device-scope release (L2 writeback)
      atomicAdd(flag, 1);      // device-scope by default
    }
    return;
  }

  // ===================== B-phase (block 0 only) =====================
  if (tid == 0) {
    while (__hip_atomic_load(flag, __ATOMIC_RELAXED,
                             __HIP_MEMORY_SCOPE_AGENT) < NW - 1)
      __builtin_amdgcn_s_sleep(2);
    __threadfence();           // device-scope acquire (cache invalidate)
  }
  __syncthreads();

  unsigned char* cell = (unsigned char*)cellw;
  const float beta = betap[0];

  // issue window-0 record loads first so HBM latency hides under LDS init
  uint2 ra[4], rb[4];
#pragma unroll
  for (int k = 0; k < 4; ++k) ra[k] = recpk[tid + (k << 10)];

  for (int g = tid; g < NSITES / 4; g += 1024) {
    int4 x = ((const int4*)Xi)[g];
    // pack 4 int32 cells into one dword (byte lanes)
    cellw[g] = (unsigned)(x.x & 255) | ((unsigned)(x.y & 255) << 8) |
               ((unsigned)(x.z & 255) << 16) | ((unsigned)(x.w & 255) << 24);
  }
  if (tid < NW * RMAX) lend[tid] = ends[tid];  // NW*RMAX == 512
  // cumulative softmax table: bit-identical to per-update reference math
  for (int t = tid; t < 729; t += 1024) {
    const int n0 = t % 9, n1 = (t / 9) % 9, n2 = t / 81;
    const int n3 = 8 - n0 - n1 - n2;
    float4 val = make_float4(2.f, 2.f, 2.f, 2.f);  // unreachable combos
    if (n3 >= 0) {
      const int mx = max(max(n0, n1), max(n2, n3));
      const float xm = beta * (float)mx;   // fl(beta*mx), no FMA (contract off)
      const float x0 = beta * (float)n0;
      const float x1 = beta * (float)n1;
      const float x2 = beta * (float)n2;
      const float x3 = beta * (float)n3;
      const float e0 = (float)exp((double)(x0 - xm));
      const float e1 = (float)exp((double)(x1 - xm));
      const float e2 = (float)exp((double)(x2 - xm));
      const float e3 = (float)exp((double)(x3 - xm));
      const float s = ((e0 + e1) + e2) + e3;  // sequential sum, like np/XLA
      const float c0 = e0 / s;                // IEEE f32 divides, like ref
      const float c1 = c0 + e1 / s;
      const float c2 = c1 + e2 / s;
      const float c3 = c2 + e3 / s;
      val = make_float4(c0, c1, c2, c3);
    }
    ctab[t] = val;
  }
  __syncthreads();

  for (int ww2 = 0; ww2 < 2 * NW; ++ww2) {
    const int ww = ww2 & (NW - 1);
    const int* le = &lend[ww * RMAX];
    const int wn = ww2 + 1;  // prefetch target (guarded; pointer calc only)
    const uint2* rpn = recpk + (wn >> 4) * NSITES + (wn & (NW - 1)) * WIN;
    if ((ww2 & 1) == 0) {
      if (wn < 2 * NW) {
#pragma unroll
        for (int k = 0; k < 4; ++k) rb[k] = rpn[tid + (k << 10)];
      }
      run_rounds(cell, cellw, ctab, le, ra, tid);
    } else {
      if (wn < 2 * NW) {
#pragma unroll
        for (int k = 0; k < 4; ++k) ra[k] = rpn[tid + (k << 10)];
      }
      run_rounds(cell, cellw, ctab, le, rb, tid);
    }
  }

  for (int g = tid; g < NSITES / 4; g += 1024) {
    const unsigned p = cellw[g];
    int4 o;
    o.x = (int)(p & 255u);
    o.y = (int)((p >> 8) & 255u);
    o.z = (int)((p >> 16) & 255u);
    o.w = (int)((p >> 24) & 255u);
    ((int4*)out)[g] = o;
  }
}

extern "C" void kernel_launch(void* const* d_in, const int* in_sizes, int n_in,
                              void* d_out, int out_size, void* d_ws,
                              size_t ws_size, hipStream_t stream) {
  const int* Xi = (const int*)d_in[0];
  const int* perm = (const int*)d_in[1];
  const float* uni = (const float*)d_in[2];
  const float* beta = (const float*)d_in[3];
  int* out = (int*)d_out;

  char* ws = (char*)d_ws;
  uint2* recpk = (uint2*)ws;                             // 1 MiB
  int* ends = (int*)(ws + 2 * NSITES * 8);               // 2048 B (RMAX=32)
  int* flag = (int*)(ws + 2 * NSITES * 8 + NW * RMAX * 4);  // 4 B

  hipMemsetAsync(flag, 0, sizeof(int), stream);  // graph-captured, per-replay
  GibbsSampler_90443421319469_kernel<<<dim3(NW), dim3(1024), 0, stream>>>(
      Xi, perm, uni, beta, recpk, ends, flag, out);
}